// Round 1
// 1039.534 us; speedup vs baseline: 1.0508x; 1.0508x over previous
//
#include <hip/hip_runtime.h>
#include <math.h>

#define B_ 8
#define C_ 512
#define W_ 64
#define H_ 32
#define HID_ 256
#define G_ 1280
#define WH_ (W_*H_)           // 2048
#define CELL_STRIDE (B_*HID_) // 2048 floats per (w,h) cell in hbuf/cbuf
#define SENT 0xFFFFFFFFu      // memset(0xFF) pattern = negative quiet NaN; real h/c never NaN

typedef float v4f __attribute__((ext_vector_type(4)));

__device__ __forceinline__ float sigmoidf_(float x) {
    return 1.0f / (1.0f + __expf(-x));
}

__device__ __forceinline__ float tanhf_(float x) {
    float ax = fabsf(x);
    float e = __expf(-2.0f * ax);
    float t = (1.0f - e) / (1.0f + e);
    return copysignf(t, x);
}

// ---- device-coherent (sc0 sc1: bypass L1+L2, served at coherence point) ----
__device__ __forceinline__ void stg_byp1(float* p, float v) {
    asm volatile("global_store_dword %0, %1, off sc0 sc1" :: "v"(p), "v"(v) : "memory");
}
// canary: 2 dword bypass loads, one wait
__device__ __forceinline__ void ldg2_byp(const unsigned* p0, const unsigned* p1,
                                         unsigned& a, unsigned& b) {
    asm volatile("global_load_dword %0, %2, off sc0 sc1\n\t"
                 "global_load_dword %1, %3, off sc0 sc1\n\t"
                 "s_waitcnt vmcnt(0)"
                 : "=&v"(a), "=&v"(b)
                 : "v"(p0), "v"(p1)
                 : "memory");
}

__device__ __forceinline__ bool ok4(v4f v) {
    return (__float_as_uint(v.x) != SENT) & (__float_as_uint(v.y) != SENT) &
           (__float_as_uint(v.z) != SENT) & (__float_as_uint(v.w) != SENT);
}

// ---------------------------------------------------------------------------
// A0: transpose x (B,C,W,H) = [bc][wh] row-major  ->  xT [wh][bc]
// ---------------------------------------------------------------------------
__global__ __launch_bounds__(256) void k_transpose_x(const float* __restrict__ x,
                                                     float* __restrict__ xT) {
    __shared__ float tile[64][65];
    int bc0 = blockIdx.x * 64;
    int wh0 = blockIdx.y * 64;
    int xcol = threadIdx.x & 63;
    int yrow = threadIdx.x >> 6;
    for (int yy = yrow; yy < 64; yy += 4)
        tile[yy][xcol] = x[(size_t)(bc0 + yy) * WH_ + wh0 + xcol];
    __syncthreads();
    for (int yy = yrow; yy < 64; yy += 4)
        xT[(size_t)(wh0 + yy) * (B_*C_) + bc0 + xcol] = tile[xcol][yy];
}

// ---------------------------------------------------------------------------
// A: GEMM  xp[m][g] = sum_c A[m][c]*Wx[c][g] + bias[g],  m = wh*8+b (16384)
// BM=64, BN=128, BK=32; 256 threads; micro-tile 8m x 4n
// ---------------------------------------------------------------------------
#define BM 64
#define BN 128
#define BK 32
#define AS_STRIDE 68
#define BS_STRIDE 132

__global__ __launch_bounds__(256) void k_xproj(const float* __restrict__ xT,
                                               const float* __restrict__ Wx,
                                               const float* __restrict__ bias,
                                               float* __restrict__ xp) {
    __shared__ float As[BK * AS_STRIDE];
    __shared__ float Bs[BK * BS_STRIDE];

    int bid = blockIdx.x;
    int xcd = bid & 7;
    int slot = bid >> 3;
    int mt = xcd * 32 + slot / 10;
    int nt = slot % 10;
    int m0 = mt * BM, n0 = nt * BN;
    int tid = threadIdx.x;

    int tm  = (tid >> 5) * 8;
    int tn4 = (tid & 31) * 4;

    float4 acc[8];
#pragma unroll
    for (int i = 0; i < 8; ++i) { acc[i].x = acc[i].y = acc[i].z = acc[i].w = 0.f; }

    int ar = tid >> 2, aq = tid & 3;
    int br = tid >> 3, bq = tid & 7;

    for (int kc = 0; kc < C_; kc += BK) {
        float4 av0 = *(const float4*)(xT + (size_t)(m0 + ar) * C_ + kc + aq * 4);
        float4 av1 = *(const float4*)(xT + (size_t)(m0 + ar) * C_ + kc + (aq + 4) * 4);
        float4 bv[4];
#pragma unroll
        for (int s = 0; s < 4; ++s)
            bv[s] = *(const float4*)(Wx + (size_t)(kc + br) * G_ + n0 + (bq + 8 * s) * 4);

        __syncthreads();
        As[(aq * 4 + 0) * AS_STRIDE + ar] = av0.x;
        As[(aq * 4 + 1) * AS_STRIDE + ar] = av0.y;
        As[(aq * 4 + 2) * AS_STRIDE + ar] = av0.z;
        As[(aq * 4 + 3) * AS_STRIDE + ar] = av0.w;
        As[((aq + 4) * 4 + 0) * AS_STRIDE + ar] = av1.x;
        As[((aq + 4) * 4 + 1) * AS_STRIDE + ar] = av1.y;
        As[((aq + 4) * 4 + 2) * AS_STRIDE + ar] = av1.z;
        As[((aq + 4) * 4 + 3) * AS_STRIDE + ar] = av1.w;
#pragma unroll
        for (int s = 0; s < 4; ++s)
            *(float4*)&Bs[br * BS_STRIDE + (bq + 8 * s) * 4] = bv[s];
        __syncthreads();

#pragma unroll
        for (int k = 0; k < BK; ++k) {
            float4 a0 = *(const float4*)&As[k * AS_STRIDE + tm];
            float4 a1 = *(const float4*)&As[k * AS_STRIDE + tm + 4];
            float4 b0 = *(const float4*)&Bs[k * BS_STRIDE + tn4];
            float am[8] = {a0.x, a0.y, a0.z, a0.w, a1.x, a1.y, a1.z, a1.w};
#pragma unroll
            for (int i = 0; i < 8; ++i) {
                acc[i].x += am[i] * b0.x;
                acc[i].y += am[i] * b0.y;
                acc[i].z += am[i] * b0.z;
                acc[i].w += am[i] * b0.w;
            }
        }
    }

    float4 bb = *(const float4*)(bias + n0 + tn4);
#pragma unroll
    for (int i = 0; i < 8; ++i) {
        float4 o;
        o.x = acc[i].x + bb.x; o.y = acc[i].y + bb.y;
        o.z = acc[i].z + bb.z; o.w = acc[i].w + bb.w;
        *(float4*)(xp + (size_t)(m0 + tm + i) * G_ + n0 + tn4) = o;
    }
}

// ---------------------------------------------------------------------------
// B: persistent wavefront scan. 256 blocks (1/CU, 96KB LDS), 512 threads.
// Block bid handles rows w = (bid>>3) and (bid>>3)+32, n-tile nt = bid&7.
// NEW (this round): flagless sentinel protocol. hbuf/cbuf are pre-filled with
// 0xFFFFFFFF (NaN); producers fire-and-forget sc0sc1 stores (no drain, no
// flag); consumers poll the data itself (dword != sentinel  <=>  arrived).
// Two-phase poll: 8B/wave canary spin (cheap during ramp), then one batched
// full stage+verify (converges in 1-2 iters). c_left carried in a register
// (same block produced it last h-step) - one fewer fabric round trip.
// ---------------------------------------------------------------------------
#define NT 32
#define NSL 16                      // K-slices
#define GP_B_STRIDE (NSL*160 + 8)   // 2568

__global__ __launch_bounds__(512, 2) void k_scan(const float* __restrict__ xp,
                                                 const float* __restrict__ Wh1,
                                                 const float* __restrict__ Wh2,
                                                 float* __restrict__ hbuf,
                                                 float* __restrict__ cbuf) {
    __shared__ float hs[2][B_ * HID_];        // 16 KB ([0] reused as fin)
    __shared__ float gp[B_ * GP_B_STRIDE];    // 80.25 KB

    int w0b = blockIdx.x >> 3;
    int nt  = blockIdx.x & 7;
    int n0  = nt * NT;
    int tid = threadIdx.x;

    int kq  = tid >> 5;             // 0..15
    int c0  = tid & 31;
    int sel = kq >> 3;              // 0: Wh1/h_left, 1: Wh2/h_up (wave-uniform)
    int kk0 = (kq & 7) * 32;
    const float* Wm = sel ? Wh2 : Wh1;
    const float* hbase = &hs[sel][0];

    // ---- one-time: weights into registers (160 VGPRs/AGPRs) ----
    float wr[5][32];
#pragma unroll
    for (int g = 0; g < 5; ++g)
#pragma unroll
        for (int k = 0; k < 32; ++k)
            wr[g][k] = Wm[(size_t)(kk0 + k) * G_ + g * 256 + n0 + c0];

    int b2 = tid >> 5, nn2 = tid & 31;   // update mapping (tid < 256)
    bool cok = (tid < 256);

    // ---- hoisted xp-prefetch / reduce / update index math (step-invariant) ----
    int xo[3], gpo[3], fo[3];
    bool xv[3];
#pragma unroll
    for (int t = 0; t < 3; ++t) {
        int idx = tid + 512 * t;
        xv[t] = (idx < 1280);
        int xb = xv[t] ? (idx / 160) : 0;
        int xc = idx - xb * 160;
        xo[t]  = xb * G_ + (xc >> 5) * 256 + n0 + (xc & 31);
        gpo[t] = xb * GP_B_STRIDE + xc;
        fo[t]  = xb * 160 + xc;
    }
    int gw = kq * 160 + c0;          // gp write base
    int fb = b2 * 160 + nn2;         // fin read base
    int co = b2 * HID_ + n0 + nn2;   // cell column offset

    for (int rr = 0; rr < 2; ++rr) {
        int w = w0b + rr * 32;
        float creg = 0.f;            // c_left register carry (valid for tid<256)
        for (int h = 0; h < H_; ++h) {
            int wh = w * H_ + h;

            // ---- xp prefetch (cached loads; latency hides under the poll) ----
            const float* xrow = xp + (size_t)wh * (B_ * G_);
            float xpre[3];
#pragma unroll
            for (int t = 0; t < 3; ++t)
                if (xv[t]) xpre[t] = xrow[xo[t]];

            bool vl = (h > 0), vu = (w > 0);
            const float* pl = vl ? hbuf + (size_t)(wh - 1)  * CELL_STRIDE + tid * 4 : hbuf;
            const float* pu = vu ? hbuf + (size_t)(wh - H_) * CELL_STRIDE + tid * 4 : hbuf;
            const float* pc = (vu && cok) ? cbuf + (size_t)(wh - H_) * CELL_STRIDE + co : cbuf;

            // ---- phase 1: canary spin (lane 0 of each wave, 8B per retry) ----
            if ((tid & 63) == 0) {
                if (vl | vu) {
                    for (;;) {
                        unsigned a, bvv;
                        ldg2_byp((const unsigned*)pl, (const unsigned*)pu, a, bvv);
                        if ((((!vl)) | (a != SENT)) & (((!vu)) | (bvv != SENT))) break;
                        __builtin_amdgcn_s_sleep(2);
                    }
                }
            }

            // ---- phase 2: batched full stage + verify (usually 1 iteration) ----
            v4f l0 = {0.f, 0.f, 0.f, 0.f};
            v4f u0 = {0.f, 0.f, 0.f, 0.f};
            float cu = 0.f;
            bool needl = vl, needu = vu, needc = vu && cok;
            for (;;) {
                v4f tl, tu; float tc;
                asm volatile(
                    "global_load_dwordx4 %0, %3, off sc0 sc1\n\t"
                    "global_load_dwordx4 %1, %4, off sc0 sc1\n\t"
                    "global_load_dword %2, %5, off sc0 sc1\n\t"
                    "s_waitcnt vmcnt(0)"
                    : "=&v"(tl), "=&v"(tu), "=&v"(tc)
                    : "v"(pl), "v"(pu), "v"(pc)
                    : "memory");
                if (needl & ok4(tl)) { l0 = tl; needl = false; }
                if (needu & ok4(tu)) { u0 = tu; needu = false; }
                if (needc & (__float_as_uint(tc) != SENT)) { cu = tc; needc = false; }
                if (__ballot(needl | needu | needc) == 0) break;
                __builtin_amdgcn_s_sleep(1);
            }
            ((v4f*)hs[0])[tid] = l0;
            ((v4f*)hs[1])[tid] = u0;
            __syncthreads();

            // ---- GEMM: pure LDS + FMA (no VMEM) ----
            float acc[5][8];
#pragma unroll
            for (int g = 0; g < 5; ++g)
#pragma unroll
                for (int b = 0; b < 8; ++b) acc[g][b] = 0.f;

#pragma unroll
            for (int k4 = 0; k4 < 8; ++k4) {
#pragma unroll
                for (int b = 0; b < 8; ++b) {
                    float4 hv = *(const float4*)&hbase[b * HID_ + kk0 + k4 * 4]; // broadcast
#pragma unroll
                    for (int g = 0; g < 5; ++g) {
                        acc[g][b] += hv.x * wr[g][k4 * 4 + 0];
                        acc[g][b] += hv.y * wr[g][k4 * 4 + 1];
                        acc[g][b] += hv.z * wr[g][k4 * 4 + 2];
                        acc[g][b] += hv.w * wr[g][k4 * 4 + 3];
                    }
                }
            }

            // partials gp[b][kq][c]
#pragma unroll
            for (int g = 0; g < 5; ++g)
#pragma unroll
                for (int b = 0; b < 8; ++b)
                    gp[b * GP_B_STRIDE + gw + g * 32] = acc[g][b];
            __syncthreads();

            // ---- reduce 16 K-slices + xp -> fin (= hs[0]) ----
            float* fin = hs[0];
#pragma unroll
            for (int t = 0; t < 3; ++t) {
                if (xv[t]) {
                    float s = xpre[t];
#pragma unroll
                    for (int q = 0; q < NSL; ++q)
                        s += gp[gpo[t] + q * 160];
                    fin[fo[t]] = s;
                }
            }
            __syncthreads();

            // ---- cell update (tid < 256); stores are fire-and-forget ----
            if (cok) {
                float iv = sigmoidf_(fin[fb + 0 * 32]);
                float f1 = sigmoidf_(fin[fb + 1 * 32]);
                float f2 = sigmoidf_(fin[fb + 2 * 32]);
                float ov = sigmoidf_(fin[fb + 3 * 32]);
                float cd = tanhf_(fin[fb + 4 * 32]);
                float cv = iv * cd + f1 * creg + f2 * cu;
                float hh = ov * tanhf_(cv);
                creg = cv;
                stg_byp1(cbuf + (size_t)wh * CELL_STRIDE + co, cv);
                stg_byp1(hbuf + (size_t)wh * CELL_STRIDE + co, hh);
            }
            __syncthreads();    // fin reads done before next step's hs writes
        }
    }
}

// ---------------------------------------------------------------------------
// C1: BN partial stats
// ---------------------------------------------------------------------------
__global__ __launch_bounds__(256) void k_stats(const float* __restrict__ hbuf,
                                               float* __restrict__ ssum,
                                               float* __restrict__ ssq) {
    int t = threadIdx.x;
    size_t r0 = (size_t)blockIdx.x * 64;
    float s = 0.f, q = 0.f;
    for (int r = 0; r < 64; ++r) {
        float v = hbuf[(r0 + r) * HID_ + t];
        s += v; q += v * v;
    }
    atomicAdd(&ssum[t], s);
    atomicAdd(&ssq[t], q);
}

__global__ void k_finstats(const float* __restrict__ ssum, const float* __restrict__ ssq,
                           float* __restrict__ mean, float* __restrict__ rinv) {
    int t = threadIdx.x;
    const float inv_n = 1.0f / 16384.0f;
    float m = ssum[t] * inv_n;
    float v = ssq[t] * inv_n - m * m;
    mean[t] = m;
    rinv[t] = rsqrtf(v + 1e-5f);
}

// ---------------------------------------------------------------------------
// C2: transpose (wh,b,n) -> (b,n,wh); fused BN+tanh for out
// ---------------------------------------------------------------------------
__global__ __launch_bounds__(256) void k_out(const float* __restrict__ hbuf,
                                             const float* __restrict__ cbuf,
                                             const float* __restrict__ mean,
                                             const float* __restrict__ rinv,
                                             const float* __restrict__ gamma,
                                             const float* __restrict__ beta,
                                             float* __restrict__ outp) {
    __shared__ float tile[64][65];
    int bi = blockIdx.x;
    int b = bi >> 7;
    int rem = bi & 127;
    int wh0 = (rem >> 2) * 64;
    int n0 = (rem & 3) * 64;
    int xcol = threadIdx.x & 63;
    int yrow = threadIdx.x >> 6;

    float* out0   = outp;
    float* state0 = outp + (size_t)B_ * HID_ * WH_;
    float* cell0  = state0 + (size_t)B_ * HID_ * WH_;

    for (int yy = yrow; yy < 64; yy += 4)
        tile[yy][xcol] = hbuf[((size_t)(wh0 + yy) * B_ + b) * HID_ + n0 + xcol];
    __syncthreads();
    for (int yy = yrow; yy < 64; yy += 4) {
        int n = n0 + yy;
        float sv = tile[xcol][yy];
        size_t oidx = ((size_t)b * HID_ + n) * WH_ + wh0 + xcol;
        state0[oidx] = sv;
        float xn = (sv - mean[n]) * rinv[n];
        out0[oidx] = tanhf_(xn * gamma[n] + beta[n]);
    }
    __syncthreads();

    for (int yy = yrow; yy < 64; yy += 4)
        tile[yy][xcol] = cbuf[((size_t)(wh0 + yy) * B_ + b) * HID_ + n0 + xcol];
    __syncthreads();

    for (int yy = yrow; yy < 64; yy += 4) {
        int n = n0 + yy;
        size_t oidx = ((size_t)b * HID_ + n) * WH_ + wh0 + xcol;
        cell0[oidx] = tile[xcol][yy];
    }
}

// ---------------------------------------------------------------------------
extern "C" void kernel_launch(void* const* d_in, const int* in_sizes, int n_in,
                              void* d_out, int out_size, void* d_ws, size_t ws_size,
                              hipStream_t stream) {
    const float* x     = (const float*)d_in[0];
    const float* Wx    = (const float*)d_in[1];
    const float* Wh1   = (const float*)d_in[2];
    const float* Wh2   = (const float*)d_in[3];
    const float* bias  = (const float*)d_in[4];
    const float* gamma = (const float*)d_in[5];
    const float* beta  = (const float*)d_in[6];
    float* out = (float*)d_out;
    float* ws  = (float*)d_ws;

    float* xp   = ws;                       // 20,971,520 floats
    float* xT   = ws + 20971520;            // 8,388,608 floats (dead after xproj)
    float* hbuf = xT;                       // alias (4,194,304 floats)
    float* cbuf = xT + 4194304;             // alias (4,194,304 floats)
    float* ssum = ws + 29360128;
    float* ssq  = ssum + 256;
    float* mean = ssum + 512;
    float* rinv = ssum + 768;

    k_transpose_x<<<dim3(64, 32), 256, 0, stream>>>(x, xT);
    k_xproj<<<2560, 256, 0, stream>>>(xT, Wx, bias, xp);

    hipMemsetAsync(ssum, 0, 1024 * sizeof(float), stream);
    // sentinel-fill hbuf+cbuf (contiguous 8M floats); runs after xproj (alias)
    hipMemsetAsync(hbuf, 0xFF, (size_t)8388608 * sizeof(float), stream);

    k_scan<<<256, 512, 0, stream>>>(xp, Wh1, Wh2, hbuf, cbuf);

    k_stats<<<256, 256, 0, stream>>>(hbuf, ssum, ssq);
    k_finstats<<<1, 256, 0, stream>>>(ssum, ssq, mean, rinv);
    k_out<<<8 * 32 * 4, 256, 0, stream>>>(hbuf, cbuf, mean, rinv, gamma, beta, out);
}

// Round 2
// 1025.494 us; speedup vs baseline: 1.0652x; 1.0137x over previous
//
#include <hip/hip_runtime.h>
#include <math.h>

#define B_ 8
#define C_ 512
#define W_ 64
#define H_ 32
#define HID_ 256
#define G_ 1280
#define WH_ (W_*H_)           // 2048
#define CELL_STRIDE (B_*HID_) // 2048 floats per (w,h) cell in hbuf/cbuf
#define SENT 0xFFFFFFFFu      // memset(0xFF) pattern = negative quiet NaN; real h/c never NaN

typedef float v4f __attribute__((ext_vector_type(4)));

__device__ __forceinline__ float sigmoidf_(float x) {
    return 1.0f / (1.0f + __expf(-x));
}

__device__ __forceinline__ float tanhf_(float x) {
    float ax = fabsf(x);
    float e = __expf(-2.0f * ax);
    float t = (1.0f - e) / (1.0f + e);
    return copysignf(t, x);
}

// ---- device-coherent (sc0 sc1: bypass L1+L2, served at coherence point) ----
__device__ __forceinline__ void stg_byp1(float* p, float v) {
    asm volatile("global_store_dword %0, %1, off sc0 sc1" :: "v"(p), "v"(v) : "memory");
}
// canary: 2 dword bypass loads, one wait
__device__ __forceinline__ void ldg2_byp(const unsigned* p0, const unsigned* p1,
                                         unsigned& a, unsigned& b) {
    asm volatile("global_load_dword %0, %2, off sc0 sc1\n\t"
                 "global_load_dword %1, %3, off sc0 sc1\n\t"
                 "s_waitcnt vmcnt(0)"
                 : "=&v"(a), "=&v"(b)
                 : "v"(p0), "v"(p1)
                 : "memory");
}

__device__ __forceinline__ bool ok4(v4f v) {
    return (__float_as_uint(v.x) != SENT) & (__float_as_uint(v.y) != SENT) &
           (__float_as_uint(v.z) != SENT) & (__float_as_uint(v.w) != SENT);
}

// ---------------------------------------------------------------------------
// A0: transpose x (B,C,W,H) = [bc][wh] row-major  ->  xT [wh][bc]
// ---------------------------------------------------------------------------
__global__ __launch_bounds__(256) void k_transpose_x(const float* __restrict__ x,
                                                     float* __restrict__ xT) {
    __shared__ float tile[64][65];
    int bc0 = blockIdx.x * 64;
    int wh0 = blockIdx.y * 64;
    int xcol = threadIdx.x & 63;
    int yrow = threadIdx.x >> 6;
    for (int yy = yrow; yy < 64; yy += 4)
        tile[yy][xcol] = x[(size_t)(bc0 + yy) * WH_ + wh0 + xcol];
    __syncthreads();
    for (int yy = yrow; yy < 64; yy += 4)
        xT[(size_t)(wh0 + yy) * (B_*C_) + bc0 + xcol] = tile[xcol][yy];
}

// ---------------------------------------------------------------------------
// A: GEMM  xp[m][g] = sum_c A[m][c]*Wx[c][g] + bias[g],  m = wh*8+b (16384)
// BM=64, BN=128, BK=32; 256 threads; micro-tile 8m x 4n
// ---------------------------------------------------------------------------
#define BM 64
#define BN 128
#define BK 32
#define AS_STRIDE 68
#define BS_STRIDE 132

__global__ __launch_bounds__(256) void k_xproj(const float* __restrict__ xT,
                                               const float* __restrict__ Wx,
                                               const float* __restrict__ bias,
                                               float* __restrict__ xp) {
    __shared__ float As[BK * AS_STRIDE];
    __shared__ float Bs[BK * BS_STRIDE];

    int bid = blockIdx.x;
    int xcd = bid & 7;
    int slot = bid >> 3;
    int mt = xcd * 32 + slot / 10;
    int nt = slot % 10;
    int m0 = mt * BM, n0 = nt * BN;
    int tid = threadIdx.x;

    int tm  = (tid >> 5) * 8;
    int tn4 = (tid & 31) * 4;

    float4 acc[8];
#pragma unroll
    for (int i = 0; i < 8; ++i) { acc[i].x = acc[i].y = acc[i].z = acc[i].w = 0.f; }

    int ar = tid >> 2, aq = tid & 3;
    int br = tid >> 3, bq = tid & 7;

    for (int kc = 0; kc < C_; kc += BK) {
        float4 av0 = *(const float4*)(xT + (size_t)(m0 + ar) * C_ + kc + aq * 4);
        float4 av1 = *(const float4*)(xT + (size_t)(m0 + ar) * C_ + kc + (aq + 4) * 4);
        float4 bv[4];
#pragma unroll
        for (int s = 0; s < 4; ++s)
            bv[s] = *(const float4*)(Wx + (size_t)(kc + br) * G_ + n0 + (bq + 8 * s) * 4);

        __syncthreads();
        As[(aq * 4 + 0) * AS_STRIDE + ar] = av0.x;
        As[(aq * 4 + 1) * AS_STRIDE + ar] = av0.y;
        As[(aq * 4 + 2) * AS_STRIDE + ar] = av0.z;
        As[(aq * 4 + 3) * AS_STRIDE + ar] = av0.w;
        As[((aq + 4) * 4 + 0) * AS_STRIDE + ar] = av1.x;
        As[((aq + 4) * 4 + 1) * AS_STRIDE + ar] = av1.y;
        As[((aq + 4) * 4 + 2) * AS_STRIDE + ar] = av1.z;
        As[((aq + 4) * 4 + 3) * AS_STRIDE + ar] = av1.w;
#pragma unroll
        for (int s = 0; s < 4; ++s)
            *(float4*)&Bs[br * BS_STRIDE + (bq + 8 * s) * 4] = bv[s];
        __syncthreads();

#pragma unroll
        for (int k = 0; k < BK; ++k) {
            float4 a0 = *(const float4*)&As[k * AS_STRIDE + tm];
            float4 a1 = *(const float4*)&As[k * AS_STRIDE + tm + 4];
            float4 b0 = *(const float4*)&Bs[k * BS_STRIDE + tn4];
            float am[8] = {a0.x, a0.y, a0.z, a0.w, a1.x, a1.y, a1.z, a1.w};
#pragma unroll
            for (int i = 0; i < 8; ++i) {
                acc[i].x += am[i] * b0.x;
                acc[i].y += am[i] * b0.y;
                acc[i].z += am[i] * b0.z;
                acc[i].w += am[i] * b0.w;
            }
        }
    }

    float4 bb = *(const float4*)(bias + n0 + tn4);
#pragma unroll
    for (int i = 0; i < 8; ++i) {
        float4 o;
        o.x = acc[i].x + bb.x; o.y = acc[i].y + bb.y;
        o.z = acc[i].z + bb.z; o.w = acc[i].w + bb.w;
        *(float4*)(xp + (size_t)(m0 + tm + i) * G_ + n0 + tn4) = o;
    }
}

// ---------------------------------------------------------------------------
// B: persistent wavefront scan. 256 blocks (1/CU), 512 threads.
// Flagless sentinel protocol (r1, proven): hbuf/cbuf pre-filled 0xFF; data
// itself is the ready flag; producers fire-and-forget sc0sc1 stores.
// NEW (this round) - LDS-pipe diet (step was LDS-throughput bound):
//  * v_permlane32_swap_b32 + add folds kq-pair partials in-wave: 16 slices->8,
//    gp writes 40->20/thread (packed via cndmask), gp LDS 80KB->41KB.
//  * ownership-aligned reduce: thread (b,c) (tid<256) reduces exactly its 5
//    gate values -> gates stay in registers; fin buffer + its barrier GONE.
//  * 2 barriers/step (was 4). Waves 4-7 start next poll during update.
// ---------------------------------------------------------------------------
#define NT 32
#define NWV 8                       // gp slices after in-wave pair reduction
#define GPS (NWV*160 + 8)           // 1288 floats per batch

__global__ __launch_bounds__(512, 2) void k_scan(const float* __restrict__ xp,
                                                 const float* __restrict__ Wh1,
                                                 const float* __restrict__ Wh2,
                                                 float* __restrict__ hbuf,
                                                 float* __restrict__ cbuf) {
    __shared__ float hs[2][B_ * HID_];        // 16 KB
    __shared__ float gp[B_ * GPS];            // 41.2 KB

    int w0b = blockIdx.x >> 3;
    int nt  = blockIdx.x & 7;
    int n0  = nt * NT;
    int tid = threadIdx.x;

    int kq  = tid >> 5;             // 0..15
    int c0  = tid & 31;
    int sel = kq >> 3;              // 0: Wh1/h_left, 1: Wh2/h_up (wave-uniform)
    int kk0 = (kq & 7) * 32;
    const float* Wm = sel ? Wh2 : Wh1;
    const float* hbase = &hs[sel][0];
    int wv = tid >> 6;              // wave id 0..7 (= kq-pair slice)
    bool lo32 = (tid & 63) < 32;

    // ---- one-time: weights into registers (160 VGPRs/AGPRs) ----
    float wr[5][32];
#pragma unroll
    for (int g = 0; g < 5; ++g)
#pragma unroll
        for (int k = 0; k < 32; ++k)
            wr[g][k] = Wm[(size_t)(kk0 + k) * G_ + g * 256 + n0 + c0];

    int b2 = tid >> 5, nn2 = tid & 31;   // (b,c) ownership for tid<256
    bool cok = (tid < 256);
    int xob = b2 * G_ + n0 + nn2;        // xp offset base (per gate +g*256)
    int co  = b2 * HID_ + n0 + nn2;      // cell column offset
    int gr  = b2 * GPS + nn2;            // gp read base
    int gwb = wv * 160 + c0;             // gp write base (slice = wave)

    for (int rr = 0; rr < 2; ++rr) {
        int w = w0b + rr * 32;
        float creg = 0.f;            // c_left register carry (valid for tid<256)
        for (int h = 0; h < H_; ++h) {
            int wh = w * H_ + h;

            // ---- xp prefetch: owner threads load their 5 gate values ----
            float xpre[5];
            if (cok) {
                const float* xrow = xp + (size_t)wh * (B_ * G_) + xob;
#pragma unroll
                for (int g = 0; g < 5; ++g) xpre[g] = xrow[g * 256];
            }

            bool vl = (h > 0), vu = (w > 0);
            const float* pl = vl ? hbuf + (size_t)(wh - 1)  * CELL_STRIDE + tid * 4 : hbuf;
            const float* pu = vu ? hbuf + (size_t)(wh - H_) * CELL_STRIDE + tid * 4 : hbuf;
            const float* pc = (vu && cok) ? cbuf + (size_t)(wh - H_) * CELL_STRIDE + co : cbuf;

            // ---- phase 1: canary spin (lane 0 of each wave, 8B per retry) ----
            if ((tid & 63) == 0) {
                if (vl | vu) {
                    for (;;) {
                        unsigned a, bvv;
                        ldg2_byp((const unsigned*)pl, (const unsigned*)pu, a, bvv);
                        if ((((!vl)) | (a != SENT)) & (((!vu)) | (bvv != SENT))) break;
                        __builtin_amdgcn_s_sleep(2);
                    }
                }
            }

            // ---- phase 2: batched full stage + verify (usually 1 iteration) ----
            v4f l0 = {0.f, 0.f, 0.f, 0.f};
            v4f u0 = {0.f, 0.f, 0.f, 0.f};
            float cu = 0.f;
            bool needl = vl, needu = vu, needc = vu && cok;
            for (;;) {
                v4f tl, tu; float tc;
                asm volatile(
                    "global_load_dwordx4 %0, %3, off sc0 sc1\n\t"
                    "global_load_dwordx4 %1, %4, off sc0 sc1\n\t"
                    "global_load_dword %2, %5, off sc0 sc1\n\t"
                    "s_waitcnt vmcnt(0)"
                    : "=&v"(tl), "=&v"(tu), "=&v"(tc)
                    : "v"(pl), "v"(pu), "v"(pc)
                    : "memory");
                if (needl & ok4(tl)) { l0 = tl; needl = false; }
                if (needu & ok4(tu)) { u0 = tu; needu = false; }
                if (needc & (__float_as_uint(tc) != SENT)) { cu = tc; needc = false; }
                if (__ballot(needl | needu | needc) == 0) break;
                __builtin_amdgcn_s_sleep(1);
            }
            ((v4f*)hs[0])[tid] = l0;
            ((v4f*)hs[1])[tid] = u0;
            __syncthreads();                       // B1: hs ready

            // ---- GEMM: pure LDS + FMA (no VMEM) ----
            float acc[5][8];
#pragma unroll
            for (int g = 0; g < 5; ++g)
#pragma unroll
                for (int b = 0; b < 8; ++b) acc[g][b] = 0.f;

#pragma unroll
            for (int k4 = 0; k4 < 8; ++k4) {
#pragma unroll
                for (int b = 0; b < 8; ++b) {
                    float4 hv = *(const float4*)&hbase[b * HID_ + kk0 + k4 * 4]; // broadcast
#pragma unroll
                    for (int g = 0; g < 5; ++g) {
                        acc[g][b] += hv.x * wr[g][k4 * 4 + 0];
                        acc[g][b] += hv.y * wr[g][k4 * 4 + 1];
                        acc[g][b] += hv.z * wr[g][k4 * 4 + 2];
                        acc[g][b] += hv.w * wr[g][k4 * 4 + 3];
                    }
                }
            }

            // ---- in-wave kq-pair reduction (VALU pipe) + packed gp write ----
            // lanes i / i+32 hold partials of adjacent kq for the same c0;
            // swap+add gives the pair sum in all lanes. Halves store value
            // v (lo) / v+20 (hi): 20 LDS stores instead of 40.
#pragma unroll
            for (int v = 0; v < 20; ++v) {
                const int ia = v, ib = v + 20;
                float xa = acc[ia >> 3][ia & 7], ya = xa;
                float xb = acc[ib >> 3][ib & 7], yb = xb;
                asm("v_permlane32_swap_b32 %0, %1" : "+v"(xa), "+v"(ya));
                asm("v_permlane32_swap_b32 %0, %1" : "+v"(xb), "+v"(yb));
                float sa = xa + ya;
                float sb = xb + yb;
                float val = lo32 ? sa : sb;
                const int offA = (ia & 7) * GPS + (ia >> 3) * 32;
                const int offB = (ib & 7) * GPS + (ib >> 3) * 32;
                gp[gwb + (lo32 ? offA : offB)] = val;
            }
            __syncthreads();                       // B2: gp ready, GEMM reads done

            // ---- ownership-aligned reduce + cell update (tid < 256) ----
            // gates computed straight into registers; no fin buffer.
            if (cok) {
                float gv[5];
#pragma unroll
                for (int g = 0; g < 5; ++g) {
                    float s = xpre[g];
#pragma unroll
                    for (int q = 0; q < NWV; ++q)
                        s += gp[gr + q * 160 + g * 32];
                    gv[g] = s;
                }
                float iv = sigmoidf_(gv[0]);
                float f1 = sigmoidf_(gv[1]);
                float f2 = sigmoidf_(gv[2]);
                float ov = sigmoidf_(gv[3]);
                float cd = tanhf_(gv[4]);
                float cv = iv * cd + f1 * creg + f2 * cu;
                float hh = ov * tanhf_(cv);
                creg = cv;
                stg_byp1(cbuf + (size_t)wh * CELL_STRIDE + co, cv);
                stg_byp1(hbuf + (size_t)wh * CELL_STRIDE + co, hh);
            }
            // no trailing barrier: next step's hs writes are post-B2 for every
            // wave (GEMM reads done); next gp writes are post-B1 (reduce done).
        }
    }
}

// ---------------------------------------------------------------------------
// C1: BN partial stats
// ---------------------------------------------------------------------------
__global__ __launch_bounds__(256) void k_stats(const float* __restrict__ hbuf,
                                               float* __restrict__ ssum,
                                               float* __restrict__ ssq) {
    int t = threadIdx.x;
    size_t r0 = (size_t)blockIdx.x * 64;
    float s = 0.f, q = 0.f;
    for (int r = 0; r < 64; ++r) {
        float v = hbuf[(r0 + r) * HID_ + t];
        s += v; q += v * v;
    }
    atomicAdd(&ssum[t], s);
    atomicAdd(&ssq[t], q);
}

__global__ void k_finstats(const float* __restrict__ ssum, const float* __restrict__ ssq,
                           float* __restrict__ mean, float* __restrict__ rinv) {
    int t = threadIdx.x;
    const float inv_n = 1.0f / 16384.0f;
    float m = ssum[t] * inv_n;
    float v = ssq[t] * inv_n - m * m;
    mean[t] = m;
    rinv[t] = rsqrtf(v + 1e-5f);
}

// ---------------------------------------------------------------------------
// C2: transpose (wh,b,n) -> (b,n,wh); fused BN+tanh for out
// ---------------------------------------------------------------------------
__global__ __launch_bounds__(256) void k_out(const float* __restrict__ hbuf,
                                             const float* __restrict__ cbuf,
                                             const float* __restrict__ mean,
                                             const float* __restrict__ rinv,
                                             const float* __restrict__ gamma,
                                             const float* __restrict__ beta,
                                             float* __restrict__ outp) {
    __shared__ float tile[64][65];
    int bi = blockIdx.x;
    int b = bi >> 7;
    int rem = bi & 127;
    int wh0 = (rem >> 2) * 64;
    int n0 = (rem & 3) * 64;
    int xcol = threadIdx.x & 63;
    int yrow = threadIdx.x >> 6;

    float* out0   = outp;
    float* state0 = outp + (size_t)B_ * HID_ * WH_;
    float* cell0  = state0 + (size_t)B_ * HID_ * WH_;

    for (int yy = yrow; yy < 64; yy += 4)
        tile[yy][xcol] = hbuf[((size_t)(wh0 + yy) * B_ + b) * HID_ + n0 + xcol];
    __syncthreads();
    for (int yy = yrow; yy < 64; yy += 4) {
        int n = n0 + yy;
        float sv = tile[xcol][yy];
        size_t oidx = ((size_t)b * HID_ + n) * WH_ + wh0 + xcol;
        state0[oidx] = sv;
        float xn = (sv - mean[n]) * rinv[n];
        out0[oidx] = tanhf_(xn * gamma[n] + beta[n]);
    }
    __syncthreads();

    for (int yy = yrow; yy < 64; yy += 4)
        tile[yy][xcol] = cbuf[((size_t)(wh0 + yy) * B_ + b) * HID_ + n0 + xcol];
    __syncthreads();

    for (int yy = yrow; yy < 64; yy += 4) {
        int n = n0 + yy;
        size_t oidx = ((size_t)b * HID_ + n) * WH_ + wh0 + xcol;
        cell0[oidx] = tile[xcol][yy];
    }
}

// ---------------------------------------------------------------------------
extern "C" void kernel_launch(void* const* d_in, const int* in_sizes, int n_in,
                              void* d_out, int out_size, void* d_ws, size_t ws_size,
                              hipStream_t stream) {
    const float* x     = (const float*)d_in[0];
    const float* Wx    = (const float*)d_in[1];
    const float* Wh1   = (const float*)d_in[2];
    const float* Wh2   = (const float*)d_in[3];
    const float* bias  = (const float*)d_in[4];
    const float* gamma = (const float*)d_in[5];
    const float* beta  = (const float*)d_in[6];
    float* out = (float*)d_out;
    float* ws  = (float*)d_ws;

    float* xp   = ws;                       // 20,971,520 floats
    float* xT   = ws + 20971520;            // 8,388,608 floats (dead after xproj)
    float* hbuf = xT;                       // alias (4,194,304 floats)
    float* cbuf = xT + 4194304;             // alias (4,194,304 floats)
    float* ssum = ws + 29360128;
    float* ssq  = ssum + 256;
    float* mean = ssum + 512;
    float* rinv = ssum + 768;

    k_transpose_x<<<dim3(64, 32), 256, 0, stream>>>(x, xT);
    k_xproj<<<2560, 256, 0, stream>>>(xT, Wx, bias, xp);

    hipMemsetAsync(ssum, 0, 1024 * sizeof(float), stream);
    // sentinel-fill hbuf+cbuf (contiguous 8M floats); runs after xproj (alias)
    hipMemsetAsync(hbuf, 0xFF, (size_t)8388608 * sizeof(float), stream);

    k_scan<<<256, 512, 0, stream>>>(xp, Wh1, Wh2, hbuf, cbuf);

    k_stats<<<256, 256, 0, stream>>>(hbuf, ssum, ssq);
    k_finstats<<<1, 256, 0, stream>>>(ssum, ssq, mean, rinv);
    k_out<<<8 * 32 * 4, 256, 0, stream>>>(hbuf, cbuf, mean, rinv, gamma, beta, out);
}